// Round 11
// baseline (69.910 us; speedup 1.0000x reference)
//
#include <hip/hip_runtime.h>
#include <hip/hip_fp16.h>

#define NB 8
#define NS 1024
#define NH 8
#define NMONO 56    // monomials (a,b,c), a+b+c <= 5, graded order
#define MPART 512   // moments partial blocks

// ---------------------------------------------------------------------------
// Quantum layer collapsed analytically (verified R3-R8): c_j = cos(x_j+th_j),
//   meas[0] = c1..c7, meas[w>=1] = c0..cw;  q = meas[0:3]/8 (|q_i|<=0.125),
//   k = meas[3:6] (|k_i|<=1), v = meas[6:8].
// Linear attention via deg-5 Taylor of e^{q.k} (|q.k|<=0.375, rel err 8e-6):
// e^{q.k} ~= sum_{a+b+c<=5} [q0^a q1^b q2^c/(a!b!c!)] * [k0^a k1^b k2^c].
// Moments M^w = sum_t k^abc * w_t, w in {1,v0,v1}; att = phi(q).M^v/phi(q).M^1.
// Algorithm VERIFIED (R9/R10 pass at the 4.88e-4 harness bf16-ref floor).
// R9  lesson: __constant__ tables -> runtime indexing -> scratch spill.
// R10 lesson: constexpr+no-cap fixed most of it (108->70us); residual ~26us
//   for two ~2us kernels -> suspect partial spill from 4x-unrolled monomial
//   trees + 1 block/CU latency exposure.
// R11: unroll-1 t-loop (one tree live), moments grid 512 (2 blocks/CU),
//   eval launch_bounds(256,1).
// R5 lesson: no spin grid-barriers (~65us each).
// ---------------------------------------------------------------------------

// graded enumeration; mono[i] = mono[PRED[i]] * q[VARI[i]] (PRED folds at CT)
constexpr int PRED[NMONO] = {
    0,
    0, 0, 0,
    1, 2, 3, 2, 3, 3,
    4, 5, 6, 7, 8, 9, 7, 8, 9, 9,
    10,11,12,13,14,15,16,17,18,19,16,17,18,19,19,
    20,21,22,23,24,25,26,27,28,29,30,31,32,33,34,30,31,32,33,34,34};
constexpr int VARI[NMONO] = {
    0,
    0, 1, 2,
    0, 0, 0, 1, 1, 2,
    0, 0, 0, 0, 0, 0, 1, 1, 1, 2,
    0, 0, 0, 0, 0, 0, 0, 0, 0, 0, 1, 1, 1, 1, 2,
    0, 0, 0, 0, 0, 0, 0, 0, 0, 0, 0, 0, 0, 0, 0, 1, 1, 1, 1, 1, 2};
#define F6 0.166666666666667f
#define F12 0.0833333333333333f
#define F24 0.0416666666666667f
#define F120 0.00833333333333333f
constexpr float COEF[NMONO] = {          // 1/(a! b! c!)
    1.f,
    1.f, 1.f, 1.f,
    0.5f, 1.f, 1.f, 0.5f, 1.f, 0.5f,
    F6, 0.5f, 0.5f, 0.5f, 1.f, 0.5f, F6, 0.5f, 0.5f, F6,
    F24, F6, F6, 0.25f, 0.5f, 0.25f, F6, 0.5f, 0.5f, F6, F24, F6, 0.25f, F6, F24,
    F120, F24, F24, F12, F6, F12, F12, 0.25f, 0.25f, F12, F24, F6, 0.25f, F6, F24,
    F120, F24, F12, F12, F24, F120};

// K1: block = (bh = bid>>3, qt = bid&7 -> 128 t). Stage kv rows in LDS;
// waves 0..2 = channel {1, v0, v1}: lane accumulates 56 monomials over 2 t
// (unroll 1 -> one tree live); LDS-transpose reduce (stride 57, conflict-
// free); write 168 partials with COEF folded in.
__global__ __launch_bounds__(256, 2) void moments_kernel(
        const float* __restrict__ x, const float* __restrict__ theta,
        float* __restrict__ part) {
    __shared__ float4 kv4[128];               // (k0,k1,k2,v0)
    __shared__ float  v1l[128];
    __shared__ float  red[3][64][57];         // 43.7 KB

    const int tid = threadIdx.x;
    const int bh = blockIdx.x >> 3;
    const int qt = blockIdx.x & 7;
    const int b = bh >> 3, h = bh & 7;
    const int t0 = qt * 128;

    // phase A: stage 128 kv rows
    if (tid < 128) {
        float th[8];
#pragma unroll
        for (int j = 0; j < 8; ++j) th[j] = theta[j];
        int t = t0 + tid;
        const float4* xp = (const float4*)(x + ((size_t)(b * NS + t)) * 64 + h * 8);
        float4 lo = xp[0], hi = xp[1];
        float c0 = __cosf(lo.x + th[0]);
        float c1 = __cosf(lo.y + th[1]);
        float c2 = __cosf(lo.z + th[2]);
        float c3 = __cosf(lo.w + th[3]);
        float c4 = __cosf(hi.x + th[4]);
        float c5 = __cosf(hi.y + th[5]);
        float c6 = __cosf(hi.z + th[6]);
        float c7 = __cosf(hi.w + th[7]);
        float m3 = ((c0 * c1) * c2) * c3;
        float m4 = m3 * c4;
        float m5 = m4 * c5;
        float m6 = m5 * c6;
        kv4[tid] = make_float4(m3, m4, m5, m6);
        v1l[tid] = m6 * c7;
    }
    __syncthreads();

    const int w = tid >> 6, l = tid & 63;
    if (w < 3) {
        float acc[NMONO];
#pragma unroll
        for (int i = 0; i < NMONO; ++i) acc[i] = 0.f;
#pragma unroll 1
        for (int j = 0; j < 2; ++j) {          // one monomial tree live at a time
            float4 kv = kv4[l + 64 * j];
            float v1 = v1l[l + 64 * j];
            float wch = (w == 0) ? 1.f : ((w == 1) ? kv.w : v1);
            float mono[NMONO];
            mono[0] = wch;
            acc[0] += wch;
#pragma unroll
            for (int i = 1; i < NMONO; ++i) {
                float var = (VARI[i] == 0) ? kv.x : ((VARI[i] == 1) ? kv.y : kv.z);
                mono[i] = mono[PRED[i]] * var;   // PRED[i] folds to a literal
                acc[i] += mono[i];
            }
        }
#pragma unroll
        for (int i = 0; i < NMONO; ++i) red[w][l][i] = acc[i];
    }
    __syncthreads();

    if (w < 3 && l < NMONO) {
        float s0 = 0.f, s1 = 0.f, s2 = 0.f, s3 = 0.f;
#pragma unroll
        for (int r = 0; r < 16; ++r) {
            s0 += red[w][4 * r + 0][l];
            s1 += red[w][4 * r + 1][l];
            s2 += red[w][4 * r + 2][l];
            s3 += red[w][4 * r + 3][l];
        }
        part[(size_t)blockIdx.x * 168 + w * 56 + l] = ((s0 + s1) + (s2 + s3)) * COEF[l];
    }
}

// K2: block = (b = bid>>5, 32-s chunk). Combine 8 partials -> LDS; thread =
// (h = tid>>5, sl = tid&31): monomial eval + 3 dots + normalize; then fused
// 16->64 projection.
__global__ __launch_bounds__(256, 1) void eval_proj_kernel(
        const float* __restrict__ x, const float* __restrict__ theta,
        const float* __restrict__ part, const float* __restrict__ W,
        const float* __restrict__ bias, float* __restrict__ out) {
    __shared__ __align__(16) float MhL[8 * 172];   // [h][ch*56+i], padded
    __shared__ float WtL[16 * 65];
    __shared__ float biasL[64];
    __shared__ float attL[32][17];

    const int tid = threadIdx.x;
    const int b = blockIdx.x >> 5;
    const int sc = blockIdx.x & 31;
    const int s0 = sc * 32;

    // phase 0: combine partials (sum over 8 qt; COEF folded in K1)
    for (int e = tid; e < 8 * 168; e += 256) {
        int h = e / 168, idx = e - h * 168;
        const float* p = part + ((size_t)((b * 8 + h) * 8)) * 168 + idx;
        float s = ((p[0] + p[168]) + (p[336] + p[504]))
                + ((p[672] + p[840]) + (p[1008] + p[1176]));
        MhL[h * 172 + idx] = s;
    }
    for (int i = tid; i < 1024; i += 256) WtL[(i & 15) * 65 + (i >> 4)] = W[i];
    if (tid < 64) biasL[tid] = bias[tid];
    __syncthreads();

    // phase 1: attention rows via 56-dim linear attention
    {
        const int h = tid >> 5, sl = tid & 31;
        const int s = s0 + sl;
        float th[8];
#pragma unroll
        for (int j = 0; j < 8; ++j) th[j] = theta[j];
        const float4* xp = (const float4*)(x + ((size_t)(b * NS + s)) * 64 + h * 8);
        float4 lo = xp[0], hi = xp[1];
        float c0 = __cosf(lo.x + th[0]);
        float c1 = __cosf(lo.y + th[1]);
        float c2 = __cosf(lo.z + th[2]);
        float c3 = __cosf(lo.w + th[3]);
        float c4 = __cosf(hi.x + th[4]);
        float c5 = __cosf(hi.y + th[5]);
        float c6 = __cosf(hi.z + th[6]);
        float c7 = __cosf(hi.w + th[7]);
        float m1 = c0 * c1;
        float m2 = m1 * c2;
        float m0 = ((c1 * c2) * (c3 * c4)) * ((c5 * c6) * c7);
        float q0 = m0 * 0.125f, q1 = m1 * 0.125f, q2 = m2 * 0.125f;

        float mono[NMONO];
        mono[0] = 1.f;
#pragma unroll
        for (int i = 1; i < NMONO; ++i)
            mono[i] = mono[PRED[i]] * ((VARI[i] == 0) ? q0 : ((VARI[i] == 1) ? q1 : q2));

        const float4* MS = (const float4*)&MhL[h * 172];
        const float4* MA = (const float4*)&MhL[h * 172 + 56];
        const float4* MB = (const float4*)&MhL[h * 172 + 112];
        float aS = 0.f, aA = 0.f, aB = 0.f;
#pragma unroll
        for (int g = 0; g < 14; ++g) {
            float4 ms = MS[g], ma = MA[g], mb = MB[g];
            float p0 = mono[g * 4 + 0], p1 = mono[g * 4 + 1];
            float p2 = mono[g * 4 + 2], p3 = mono[g * 4 + 3];
            aS = fmaf(p0, ms.x, aS); aS = fmaf(p1, ms.y, aS);
            aS = fmaf(p2, ms.z, aS); aS = fmaf(p3, ms.w, aS);
            aA = fmaf(p0, ma.x, aA); aA = fmaf(p1, ma.y, aA);
            aA = fmaf(p2, ma.z, aA); aA = fmaf(p3, ma.w, aA);
            aB = fmaf(p0, mb.x, aB); aB = fmaf(p1, mb.y, aB);
            aB = fmaf(p2, mb.z, aB); aB = fmaf(p3, mb.w, aB);
        }
        float inv = 1.0f / aS;
        attL[sl][2 * h]     = aA * inv;
        attL[sl][2 * h + 1] = aB * inv;
    }
    __syncthreads();

    // phase 2: projection (32,16) @ W^T + bias -> (32,64)
    {
        const int e = tid & 63, rr = tid >> 6;
#pragma unroll
        for (int j = 0; j < 8; ++j) {
            int row = rr * 8 + j;
            float acc = biasL[e];
#pragma unroll
            for (int jj = 0; jj < 16; ++jj)
                acc = fmaf(attL[row][jj], WtL[jj * 65 + e], acc);
            out[((size_t)(b * NS + s0 + row)) * 64 + e] = acc;
        }
    }
}

// ---------------------------------------------------------------------------
// Fallback (R3, proven): fully fused, no workspace. Used only if ws too small.
// ---------------------------------------------------------------------------
#define NPAD 1028
#define SPB 32
__global__ __launch_bounds__(256) void fused_kernel(const float* __restrict__ x,
                                                    const float* __restrict__ theta,
                                                    const float* __restrict__ W,
                                                    const float* __restrict__ bias,
                                                    float* __restrict__ out) {
    __shared__ __half2 kvA[NH][NPAD];
    __shared__ __half2 kvB[NH][NPAD];
    __shared__ __half  kvC[NH][NPAD];
    __shared__ float   attl[SPB][17];
    __shared__ float   Wt[16][64];
    __shared__ float   bl[64];

    const int tid = threadIdx.x;
    const int b = blockIdx.x >> 5;
    const int chunk = blockIdx.x & 31;

    float th[8];
#pragma unroll
    for (int j = 0; j < 8; ++j) th[j] = theta[j];

    for (int i = tid; i < 1024; i += 256) Wt[i & 15][i >> 4] = W[i];
    if (tid < 64) bl[tid] = bias[tid];

    for (int i = 0; i < 32; ++i) {
        int r = tid + (i << 8);
        int h = r & 7, t = r >> 3;
        const float4* xp = (const float4*)(x + (((size_t)(b * NS + t)) << 6) + h * 8);
        float4 lo = xp[0], hi = xp[1];
        float c0 = __cosf(lo.x + th[0]);
        float c1 = __cosf(lo.y + th[1]);
        float c2 = __cosf(lo.z + th[2]);
        float c3 = __cosf(lo.w + th[3]);
        float c4 = __cosf(hi.x + th[4]);
        float c5 = __cosf(hi.y + th[5]);
        float c6 = __cosf(hi.z + th[6]);
        float c7 = __cosf(hi.w + th[7]);
        float m3 = ((c0 * c1) * c2) * c3;
        float m4 = m3 * c4;
        float m5 = m4 * c5;
        float m6 = m5 * c6;
        float m7 = m6 * c7;
        kvA[h][t] = __floats2half2_rn(m3, m4);
        kvB[h][t] = __floats2half2_rn(m5, m6);
        kvC[h][t] = __float2half_rn(m7);
    }
    __syncthreads();

    {
        const int h = tid >> 5;
        const int sl = tid & 31;
        const int sg = chunk * SPB + sl;
        const float4* xp = (const float4*)(x + (((size_t)(b * NS + sg)) << 6) + h * 8);
        float4 lo = xp[0], hi = xp[1];
        float c0 = __cosf(lo.x + th[0]);
        float c1 = __cosf(lo.y + th[1]);
        float c2 = __cosf(lo.z + th[2]);
        float c3 = __cosf(lo.w + th[3]);
        float c4 = __cosf(hi.x + th[4]);
        float c5 = __cosf(hi.y + th[5]);
        float c6 = __cosf(hi.z + th[6]);
        float c7 = __cosf(hi.w + th[7]);
        float m1 = c0 * c1;
        float m2 = m1 * c2;
        float m0 = ((c1 * c2) * (c3 * c4)) * ((c5 * c6) * c7);
        float q0 = m0 * 0.125f, q1 = m1 * 0.125f, q2 = m2 * 0.125f;

        float sum = 0.f, a0 = 0.f, a1 = 0.f;
#pragma unroll 4
        for (int t = 0; t < NS; ++t) {
            float2 kk = __half22float2(kvA[h][t]);
            float2 kv = __half22float2(kvB[h][t]);
            float v1 = __half2float(kvC[h][t]);
            float sc = q0 * kk.x + q1 * kk.y + q2 * kv.x;
            float e = __expf(sc);
            sum += e;
            a0 += e * kv.y;
            a1 += e * v1;
        }
        float inv = 1.0f / sum;
        attl[sl][h * 2] = a0 * inv;
        attl[sl][h * 2 + 1] = a1 * inv;
    }
    __syncthreads();

    {
        const int e = tid & 63;
        const int rr = tid >> 6;
#pragma unroll
        for (int i = 0; i < 8; ++i) {
            int sl = rr * 8 + i;
            float acc = bl[e];
#pragma unroll
            for (int j = 0; j < 16; ++j)
                acc += attl[sl][j] * Wt[j][e];
            int sg = chunk * SPB + sl;
            out[(((size_t)(b * NS + sg)) << 6) + e] = acc;
        }
    }
}

extern "C" void kernel_launch(void* const* d_in, const int* in_sizes, int n_in,
                              void* d_out, int out_size, void* d_ws, size_t ws_size,
                              hipStream_t stream) {
    const float* x     = (const float*)d_in[0];
    const float* theta = (const float*)d_in[1];
    const float* W     = (const float*)d_in[2];
    const float* bias  = (const float*)d_in[3];
    float* out = (float*)d_out;

    if (ws_size >= (size_t)MPART * 168 * sizeof(float)) {
        float* part = (float*)d_ws;        // 512 blocks x 168 floats (344 KB)
        moments_kernel<<<dim3(MPART), dim3(256), 0, stream>>>(x, theta, part);
        eval_proj_kernel<<<dim3(256), dim3(256), 0, stream>>>(x, theta, part, W, bias, out);
    } else {
        fused_kernel<<<dim3(NB * (NS / SPB)), dim3(256), 0, stream>>>(x, theta, W, bias, out);
    }
}

// Round 12
// 69.252 us; speedup vs baseline: 1.0095x; 1.0095x over previous
//
#include <hip/hip_runtime.h>
#include <hip/hip_fp16.h>

#define NB 8
#define NS 1024
#define NH 8
#define NMONO 56    // monomials (a,b,c), a+b+c <= 5, graded order
#define MPART 512   // moments partial blocks

// ---------------------------------------------------------------------------
// Quantum layer collapsed analytically (verified R3-R8): c_j = cos(x_j+th_j),
//   meas[0] = c1..c7, meas[w>=1] = c0..cw;  q = meas[0:3]/8 (|q_i|<=0.125),
//   k = meas[3:6] (|k_i|<=1), v = meas[6:8].
// Linear attention via deg-5 Taylor of e^{q.k} (|q.k|<=0.375, rel err 8e-6):
// e^{q.k} ~= sum_{a+b+c<=5} [q0^a q1^b q2^c/(a!b!c!)] * [k0^a k1^b k2^c].
// Moments M^w = sum_t k^abc * w_t, w in {1,v0,v1}; att = phi(q).M^v/phi(q).M^1.
// Algorithm VERIFIED (R9/R10/R11 pass at the 4.88e-4 harness bf16-ref floor).
// R9: __constant__ -> runtime indexing -> scratch spill (constexpr fixed it).
// R11: in-kernel occupancy/unroll changes neutral -> residual ~27us is
//   per-node launch overhead (~5-9us each) + structural fat.
// R12: moments = 192-thr blocks, no staging barrier (recompute rows in-reg);
//   eval grid 512 (2 blocks/CU).  R5: no spin grid-barriers (~65us each).
// ---------------------------------------------------------------------------

// graded enumeration; mono[i] = mono[PRED[i]] * q[VARI[i]] (PRED folds at CT)
constexpr int PRED[NMONO] = {
    0,
    0, 0, 0,
    1, 2, 3, 2, 3, 3,
    4, 5, 6, 7, 8, 9, 7, 8, 9, 9,
    10,11,12,13,14,15,16,17,18,19,16,17,18,19,19,
    20,21,22,23,24,25,26,27,28,29,30,31,32,33,34,30,31,32,33,34,34};
constexpr int VARI[NMONO] = {
    0,
    0, 1, 2,
    0, 0, 0, 1, 1, 2,
    0, 0, 0, 0, 0, 0, 1, 1, 1, 2,
    0, 0, 0, 0, 0, 0, 0, 0, 0, 0, 1, 1, 1, 1, 2,
    0, 0, 0, 0, 0, 0, 0, 0, 0, 0, 0, 0, 0, 0, 0, 1, 1, 1, 1, 1, 2};
#define F6 0.166666666666667f
#define F12 0.0833333333333333f
#define F24 0.0416666666666667f
#define F120 0.00833333333333333f
constexpr float COEF[NMONO] = {          // 1/(a! b! c!)
    1.f,
    1.f, 1.f, 1.f,
    0.5f, 1.f, 1.f, 0.5f, 1.f, 0.5f,
    F6, 0.5f, 0.5f, 0.5f, 1.f, 0.5f, F6, 0.5f, 0.5f, F6,
    F24, F6, F6, 0.25f, 0.5f, 0.25f, F6, 0.5f, 0.5f, F6, F24, F6, 0.25f, F6, F24,
    F120, F24, F24, F12, F6, F12, F12, 0.25f, 0.25f, F12, F24, F6, 0.25f, F6, F24,
    F120, F24, F12, F12, F24, F120};

// K1: block = (bh = bid>>3, qt = bid&7 -> 128 t); 192 threads = 3 waves,
// wave w = channel {1, v0, v1}. Each thread computes its 2 kv rows directly
// (no staging barrier), accumulates 56 monomials; LDS-transpose reduce
// (stride 57, 2-way-free); write 168 partials with COEF folded in.
__global__ __launch_bounds__(192) void moments_kernel(
        const float* __restrict__ x, const float* __restrict__ theta,
        float* __restrict__ part) {
    __shared__ float red[3][64][57];          // 43.7 KB

    const int tid = threadIdx.x;
    const int bh = blockIdx.x >> 3;
    const int qt = blockIdx.x & 7;
    const int b = bh >> 3, h = bh & 7;
    const int t0 = qt * 128;

    float th[8];
#pragma unroll
    for (int j = 0; j < 8; ++j) th[j] = theta[j];

    const int w = tid >> 6, l = tid & 63;

    float acc[NMONO];
#pragma unroll
    for (int i = 0; i < NMONO; ++i) acc[i] = 0.f;

#pragma unroll 1
    for (int j = 0; j < 2; ++j) {             // 2 rows per thread
        int t = t0 + l + 64 * j;
        const float4* xp = (const float4*)(x + ((size_t)(b * NS + t)) * 64 + h * 8);
        float4 lo = xp[0], hi = xp[1];
        float c0 = __cosf(lo.x + th[0]);
        float c1 = __cosf(lo.y + th[1]);
        float c2 = __cosf(lo.z + th[2]);
        float c3 = __cosf(lo.w + th[3]);
        float c4 = __cosf(hi.x + th[4]);
        float c5 = __cosf(hi.y + th[5]);
        float c6 = __cosf(hi.z + th[6]);
        float c7 = __cosf(hi.w + th[7]);
        float k0 = ((c0 * c1) * c2) * c3;     // m3
        float k1 = k0 * c4;                   // m4
        float k2 = k1 * c5;                   // m5
        float v0 = k2 * c6;                   // m6
        float v1 = v0 * c7;                   // m7
        float wch = (w == 0) ? 1.f : ((w == 1) ? v0 : v1);

        float mono[NMONO];
        mono[0] = wch;
        acc[0] += wch;
#pragma unroll
        for (int i = 1; i < NMONO; ++i) {
            float var = (VARI[i] == 0) ? k0 : ((VARI[i] == 1) ? k1 : k2);
            mono[i] = mono[PRED[i]] * var;    // PRED[i] folds to a literal
            acc[i] += mono[i];
        }
    }
#pragma unroll
    for (int i = 0; i < NMONO; ++i) red[w][l][i] = acc[i];
    __syncthreads();

    if (l < NMONO) {
        float s0 = 0.f, s1 = 0.f, s2 = 0.f, s3 = 0.f;
#pragma unroll
        for (int r = 0; r < 16; ++r) {
            s0 += red[w][4 * r + 0][l];
            s1 += red[w][4 * r + 1][l];
            s2 += red[w][4 * r + 2][l];
            s3 += red[w][4 * r + 3][l];
        }
        part[(size_t)blockIdx.x * 168 + w * 56 + l] = ((s0 + s1) + (s2 + s3)) * COEF[l];
    }
}

// K2: block = (b = bid>>6, 16-s chunk); 512 blocks -> 2/CU. Combine 8
// partials -> LDS; thread = (h = tid>>5, sl = tid&31 but only sl<16 rows...
// thread = (h, sl) with sl in 0..31 covering 16 s x 2 subslots) -- simpler:
// 256 threads = 16 s x 16 h-slots? Keep (h = tid>>5, sl = tid&31): sl<16
// threads do eval (128 active), rest help only in loads; then projection.
__global__ __launch_bounds__(256) void eval_proj_kernel(
        const float* __restrict__ x, const float* __restrict__ theta,
        const float* __restrict__ part, const float* __restrict__ W,
        const float* __restrict__ bias, float* __restrict__ out) {
    __shared__ __align__(16) float MhL[8 * 172];   // [h][ch*56+i], padded
    __shared__ float WtL[16 * 65];
    __shared__ float biasL[64];
    __shared__ float attL[16][17];

    const int tid = threadIdx.x;
    const int b = blockIdx.x >> 6;
    const int sc = blockIdx.x & 63;
    const int s0 = sc * 16;

    // phase 0: combine partials (sum over 8 qt; COEF folded in K1)
    for (int e = tid; e < 8 * 168; e += 256) {
        int h = e / 168, idx = e - h * 168;
        const float* p = part + ((size_t)((b * 8 + h) * 8)) * 168 + idx;
        float s = ((p[0] + p[168]) + (p[336] + p[504]))
                + ((p[672] + p[840]) + (p[1008] + p[1176]));
        MhL[h * 172 + idx] = s;
    }
    for (int i = tid; i < 1024; i += 256) WtL[(i & 15) * 65 + (i >> 4)] = W[i];
    if (tid < 64) biasL[tid] = bias[tid];
    __syncthreads();

    // phase 1: attention rows via 56-dim linear attention (128 threads:
    // h = tid>>4 & 7 ... use tid < 128: h = tid>>4, sl = tid&15)
    if (tid < 128) {
        const int h = tid >> 4, sl = tid & 15;
        const int s = s0 + sl;
        float th[8];
#pragma unroll
        for (int j = 0; j < 8; ++j) th[j] = theta[j];
        const float4* xp = (const float4*)(x + ((size_t)(b * NS + s)) * 64 + h * 8);
        float4 lo = xp[0], hi = xp[1];
        float c0 = __cosf(lo.x + th[0]);
        float c1 = __cosf(lo.y + th[1]);
        float c2 = __cosf(lo.z + th[2]);
        float c3 = __cosf(lo.w + th[3]);
        float c4 = __cosf(hi.x + th[4]);
        float c5 = __cosf(hi.y + th[5]);
        float c6 = __cosf(hi.z + th[6]);
        float c7 = __cosf(hi.w + th[7]);
        float m1 = c0 * c1;
        float m2 = m1 * c2;
        float m0 = ((c1 * c2) * (c3 * c4)) * ((c5 * c6) * c7);
        float q0 = m0 * 0.125f, q1 = m1 * 0.125f, q2 = m2 * 0.125f;

        float mono[NMONO];
        mono[0] = 1.f;
#pragma unroll
        for (int i = 1; i < NMONO; ++i)
            mono[i] = mono[PRED[i]] * ((VARI[i] == 0) ? q0 : ((VARI[i] == 1) ? q1 : q2));

        const float4* MS = (const float4*)&MhL[h * 172];
        const float4* MA = (const float4*)&MhL[h * 172 + 56];
        const float4* MB = (const float4*)&MhL[h * 172 + 112];
        float aS = 0.f, aA = 0.f, aB = 0.f;
#pragma unroll
        for (int g = 0; g < 14; ++g) {
            float4 ms = MS[g], ma = MA[g], mb = MB[g];
            float p0 = mono[g * 4 + 0], p1 = mono[g * 4 + 1];
            float p2 = mono[g * 4 + 2], p3 = mono[g * 4 + 3];
            aS = fmaf(p0, ms.x, aS); aS = fmaf(p1, ms.y, aS);
            aS = fmaf(p2, ms.z, aS); aS = fmaf(p3, ms.w, aS);
            aA = fmaf(p0, ma.x, aA); aA = fmaf(p1, ma.y, aA);
            aA = fmaf(p2, ma.z, aA); aA = fmaf(p3, ma.w, aA);
            aB = fmaf(p0, mb.x, aB); aB = fmaf(p1, mb.y, aB);
            aB = fmaf(p2, mb.z, aB); aB = fmaf(p3, mb.w, aB);
        }
        float inv = 1.0f / aS;
        attL[sl][2 * h]     = aA * inv;
        attL[sl][2 * h + 1] = aB * inv;
    }
    __syncthreads();

    // phase 2: projection (16,16) @ W^T + bias -> (16,64)
    {
        const int e = tid & 63, rr = tid >> 6;
#pragma unroll
        for (int j = 0; j < 4; ++j) {
            int row = rr * 4 + j;
            float acc = biasL[e];
#pragma unroll
            for (int jj = 0; jj < 16; ++jj)
                acc = fmaf(attL[row][jj], WtL[jj * 65 + e], acc);
            out[((size_t)(b * NS + s0 + row)) * 64 + e] = acc;
        }
    }
}

// ---------------------------------------------------------------------------
// Fallback (R3, proven): fully fused, no workspace. Used only if ws too small.
// ---------------------------------------------------------------------------
#define NPAD 1028
#define SPB 32
__global__ __launch_bounds__(256) void fused_kernel(const float* __restrict__ x,
                                                    const float* __restrict__ theta,
                                                    const float* __restrict__ W,
                                                    const float* __restrict__ bias,
                                                    float* __restrict__ out) {
    __shared__ __half2 kvA[NH][NPAD];
    __shared__ __half2 kvB[NH][NPAD];
    __shared__ __half  kvC[NH][NPAD];
    __shared__ float   attl[SPB][17];
    __shared__ float   Wt[16][64];
    __shared__ float   bl[64];

    const int tid = threadIdx.x;
    const int b = blockIdx.x >> 5;
    const int chunk = blockIdx.x & 31;

    float th[8];
#pragma unroll
    for (int j = 0; j < 8; ++j) th[j] = theta[j];

    for (int i = tid; i < 1024; i += 256) Wt[i & 15][i >> 4] = W[i];
    if (tid < 64) bl[tid] = bias[tid];

    for (int i = 0; i < 32; ++i) {
        int r = tid + (i << 8);
        int h = r & 7, t = r >> 3;
        const float4* xp = (const float4*)(x + (((size_t)(b * NS + t)) << 6) + h * 8);
        float4 lo = xp[0], hi = xp[1];
        float c0 = __cosf(lo.x + th[0]);
        float c1 = __cosf(lo.y + th[1]);
        float c2 = __cosf(lo.z + th[2]);
        float c3 = __cosf(lo.w + th[3]);
        float c4 = __cosf(hi.x + th[4]);
        float c5 = __cosf(hi.y + th[5]);
        float c6 = __cosf(hi.z + th[6]);
        float c7 = __cosf(hi.w + th[7]);
        float m3 = ((c0 * c1) * c2) * c3;
        float m4 = m3 * c4;
        float m5 = m4 * c5;
        float m6 = m5 * c6;
        float m7 = m6 * c7;
        kvA[h][t] = __floats2half2_rn(m3, m4);
        kvB[h][t] = __floats2half2_rn(m5, m6);
        kvC[h][t] = __float2half_rn(m7);
    }
    __syncthreads();

    {
        const int h = tid >> 5;
        const int sl = tid & 31;
        const int sg = chunk * SPB + sl;
        const float4* xp = (const float4*)(x + (((size_t)(b * NS + sg)) << 6) + h * 8);
        float4 lo = xp[0], hi = xp[1];
        float c0 = __cosf(lo.x + th[0]);
        float c1 = __cosf(lo.y + th[1]);
        float c2 = __cosf(lo.z + th[2]);
        float c3 = __cosf(lo.w + th[3]);
        float c4 = __cosf(hi.x + th[4]);
        float c5 = __cosf(hi.y + th[5]);
        float c6 = __cosf(hi.z + th[6]);
        float c7 = __cosf(hi.w + th[7]);
        float m1 = c0 * c1;
        float m2 = m1 * c2;
        float m0 = ((c1 * c2) * (c3 * c4)) * ((c5 * c6) * c7);
        float q0 = m0 * 0.125f, q1 = m1 * 0.125f, q2 = m2 * 0.125f;

        float sum = 0.f, a0 = 0.f, a1 = 0.f;
#pragma unroll 4
        for (int t = 0; t < NS; ++t) {
            float2 kk = __half22float2(kvA[h][t]);
            float2 kv = __half22float2(kvB[h][t]);
            float v1 = __half2float(kvC[h][t]);
            float sc = q0 * kk.x + q1 * kk.y + q2 * kv.x;
            float e = __expf(sc);
            sum += e;
            a0 += e * kv.y;
            a1 += e * v1;
        }
        float inv = 1.0f / sum;
        attl[sl][h * 2] = a0 * inv;
        attl[sl][h * 2 + 1] = a1 * inv;
    }
    __syncthreads();

    {
        const int e = tid & 63;
        const int rr = tid >> 6;
#pragma unroll
        for (int i = 0; i < 8; ++i) {
            int sl = rr * 8 + i;
            float acc = bl[e];
#pragma unroll
            for (int j = 0; j < 16; ++j)
                acc += attl[sl][j] * Wt[j][e];
            int sg = chunk * SPB + sl;
            out[(((size_t)(b * NS + sg)) << 6) + e] = acc;
        }
    }
}

extern "C" void kernel_launch(void* const* d_in, const int* in_sizes, int n_in,
                              void* d_out, int out_size, void* d_ws, size_t ws_size,
                              hipStream_t stream) {
    const float* x     = (const float*)d_in[0];
    const float* theta = (const float*)d_in[1];
    const float* W     = (const float*)d_in[2];
    const float* bias  = (const float*)d_in[3];
    float* out = (float*)d_out;

    if (ws_size >= (size_t)MPART * 168 * sizeof(float)) {
        float* part = (float*)d_ws;        // 512 blocks x 168 floats (344 KB)
        moments_kernel<<<dim3(MPART), dim3(192), 0, stream>>>(x, theta, part);
        eval_proj_kernel<<<dim3(512), dim3(256), 0, stream>>>(x, theta, part, W, bias, out);
    } else {
        fused_kernel<<<dim3(NB * (NS / SPB)), dim3(256), 0, stream>>>(x, theta, W, bias, out);
    }
}